// Round 1
// baseline (4755.994 us; speedup 1.0000x reference)
//
#include <hip/hip_runtime.h>
#include <hip/hip_bf16.h>
#include <math.h>

#define V_ 50257
#define L_ 6
#define H_ 8
#define E_ 512
#define B_ 2
#define T_ 1024
#define D_ 64
#define M_ROWS (B_*T_)   /* 2048 */
#define E3_ (3*E_)       /* 1536 */
#define E4_ (4*E_)       /* 2048 */

// ---------------- embedding: x = wte[idx] + wpe[t] ----------------
__global__ __launch_bounds__(128) void embed_kernel(
    const int* __restrict__ idx, const float* __restrict__ wte,
    const float* __restrict__ wpe, float* __restrict__ x)
{
  const int row = blockIdx.x;          // b*T + t
  const int t = row & (T_ - 1);
  const int tok = idx[row];
  float4 a = ((const float4*)(wte + (size_t)tok * E_))[threadIdx.x];
  float4 p = ((const float4*)(wpe + (size_t)t * E_))[threadIdx.x];
  float4 o; o.x = a.x + p.x; o.y = a.y + p.y; o.z = a.z + p.z; o.w = a.w + p.w;
  ((float4*)(x + (size_t)row * E_))[threadIdx.x] = o;
}

// ---------------- layernorm: one wave per row (E=512) ----------------
__global__ __launch_bounds__(64) void ln_kernel(
    const float* __restrict__ x, const float* __restrict__ g,
    const float* __restrict__ b, float* __restrict__ out)
{
  const int row = blockIdx.x;
  const int lane = threadIdx.x;
  const float4* xr = (const float4*)(x + (size_t)row * E_);
  float4 v0 = xr[lane];
  float4 v1 = xr[lane + 64];
  float s = v0.x + v0.y + v0.z + v0.w + v1.x + v1.y + v1.z + v1.w;
  float q = v0.x*v0.x + v0.y*v0.y + v0.z*v0.z + v0.w*v0.w
          + v1.x*v1.x + v1.y*v1.y + v1.z*v1.z + v1.w*v1.w;
  #pragma unroll
  for (int off = 32; off; off >>= 1) {
    s += __shfl_xor(s, off);
    q += __shfl_xor(q, off);
  }
  const float mean = s * (1.0f / E_);
  const float var  = q * (1.0f / E_) - mean * mean;
  const float rs   = 1.0f / sqrtf(var + 1e-5f);
  const float4* g4 = (const float4*)g;
  const float4* b4 = (const float4*)b;
  float4 G0 = g4[lane], G1 = g4[lane + 64];
  float4 B0 = b4[lane], B1 = b4[lane + 64];
  float4 o0, o1;
  o0.x = (v0.x - mean) * rs * G0.x + B0.x;
  o0.y = (v0.y - mean) * rs * G0.y + B0.y;
  o0.z = (v0.z - mean) * rs * G0.z + B0.z;
  o0.w = (v0.w - mean) * rs * G0.w + B0.w;
  o1.x = (v1.x - mean) * rs * G1.x + B1.x;
  o1.y = (v1.y - mean) * rs * G1.y + B1.y;
  o1.z = (v1.z - mean) * rs * G1.z + B1.z;
  o1.w = (v1.w - mean) * rs * G1.w + B1.w;
  float4* orow = (float4*)(out + (size_t)row * E_);
  orow[lane] = o0;
  orow[lane + 64] = o1;
}

// ---------------- exact GELU ----------------
__device__ __forceinline__ float gelu_exact(float v) {
  return 0.5f * v * (1.0f + erff(v * 0.70710678118654752f));
}

// ---------------- generic fp32 tiled GEMM ----------------
// C[M,N] = act(A[M,K] @ B + bias) (+ res). BT=false: B is [K,N] row-major.
// BT=true: B is [N,K] row-major (used for lm_head: wte[V,E]).
// Assumes M % BM == 0 and K % 16 == 0 (true for all calls). N guarded.
template<int BM, int BN, int TM, int TN, bool BT, bool GELU, bool RES>
__global__ __launch_bounds__(256) void gemm_kernel(
    const float* __restrict__ A, const float* __restrict__ Bm,
    const float* __restrict__ bias, const float* __restrict__ res,
    float* __restrict__ C, int M, int N, int K)
{
  constexpr int BK = 16;
  constexpr int NTX = BN / TN;
  static_assert((BM / TM) * (BN / TN) == 256, "need 256 threads");
  __shared__ float As[BK][BM + 4];
  __shared__ float Bs[BK][BN + 4];
  const int tid = threadIdx.x;
  const int m0 = blockIdx.y * BM;
  const int n0 = blockIdx.x * BN;
  const int tn = (tid % NTX) * TN;
  const int tm = (tid / NTX) * TM;
  const bool fullN = (n0 + BN <= N);
  float acc[TM][TN] = {};

  for (int kt = 0; kt < K; kt += BK) {
    __syncthreads();
    // --- stage A (transposed into LDS: As[k][m]) ---
    #pragma unroll
    for (int i = tid; i < BM * 4; i += 256) {       // BM*BK/4 float4s
      int row = i >> 2;
      int c4  = i & 3;
      float4 v = *(const float4*)(A + (size_t)(m0 + row) * K + kt + c4 * 4);
      As[c4*4 + 0][row] = v.x;
      As[c4*4 + 1][row] = v.y;
      As[c4*4 + 2][row] = v.z;
      As[c4*4 + 3][row] = v.w;
    }
    // --- stage B ---
    if (!BT) {
      constexpr int BNF = BN / 4;
      #pragma unroll
      for (int i = tid; i < BK * BNF; i += 256) {
        int krow = i / BNF;
        int c4   = i % BNF;
        int n = n0 + c4 * 4;
        float4 v;
        if (fullN) {
          v = *(const float4*)(Bm + (size_t)(kt + krow) * N + n);
        } else {
          v.x = (n + 0 < N) ? Bm[(size_t)(kt + krow) * N + n + 0] : 0.0f;
          v.y = (n + 1 < N) ? Bm[(size_t)(kt + krow) * N + n + 1] : 0.0f;
          v.z = (n + 2 < N) ? Bm[(size_t)(kt + krow) * N + n + 2] : 0.0f;
          v.w = (n + 3 < N) ? Bm[(size_t)(kt + krow) * N + n + 3] : 0.0f;
        }
        *(float4*)&Bs[krow][c4 * 4] = v;
      }
    } else {
      #pragma unroll
      for (int i = tid; i < BN * 4; i += 256) {     // BN rows x 4 float4s
        int row = i >> 2;
        int c4  = i & 3;
        float4 v = make_float4(0.0f, 0.0f, 0.0f, 0.0f);
        if (n0 + row < N)
          v = *(const float4*)(Bm + (size_t)(n0 + row) * K + kt + c4 * 4);
        Bs[c4*4 + 0][row] = v.x;
        Bs[c4*4 + 1][row] = v.y;
        Bs[c4*4 + 2][row] = v.z;
        Bs[c4*4 + 3][row] = v.w;
      }
    }
    __syncthreads();
    // --- inner product ---
    #pragma unroll
    for (int kk = 0; kk < BK; ++kk) {
      float a[TM], b[TN];
      #pragma unroll
      for (int i = 0; i < TM; i += 4) {
        float4 t4 = *(const float4*)&As[kk][tm + i];
        a[i] = t4.x; a[i+1] = t4.y; a[i+2] = t4.z; a[i+3] = t4.w;
      }
      #pragma unroll
      for (int j = 0; j < TN; j += 4) {
        float4 t4 = *(const float4*)&Bs[kk][tn + j];
        b[j] = t4.x; b[j+1] = t4.y; b[j+2] = t4.z; b[j+3] = t4.w;
      }
      #pragma unroll
      for (int i = 0; i < TM; ++i)
        #pragma unroll
        for (int j = 0; j < TN; ++j)
          acc[i][j] = fmaf(a[i], b[j], acc[i][j]);
    }
  }
  // --- epilogue ---
  #pragma unroll
  for (int i = 0; i < TM; ++i) {
    const int mrow = m0 + tm + i;
    #pragma unroll
    for (int j = 0; j < TN; ++j) {
      const int n = n0 + tn + j;
      if (n < N) {
        float v = acc[i][j];
        if (bias) v += bias[n];
        if (GELU) v = gelu_exact(v);
        if (RES)  v += res[(size_t)mrow * N + n];
        C[(size_t)mrow * N + n] = v;
      }
    }
  }
}

// ---------------- fused causal flash attention (fp32) ----------------
// qkv: [B*T, 3E] rows; head h occupies cols [h*64, h*64+64) of each third.
// Grid: (T/8, B*H), block 512 (8 waves, 1 query/wave). K tile = 64 keys.
__global__ __launch_bounds__(512) void attn_kernel(
    const float* __restrict__ qkv, float* __restrict__ y)
{
  const int bh = blockIdx.y;
  const int b  = bh >> 3;            // H_=8
  const int h  = bh & 7;
  const int qbase = blockIdx.x * 8;
  const int wid  = threadIdx.x >> 6;
  const int lane = threadIdx.x & 63;
  const int q = qbase + wid;

  __shared__ float Ks[64 * 64];      // 16B-chunk XOR-swizzled
  __shared__ float Vs[64 * 64];      // linear
  __shared__ float qs[8 * 64];
  __shared__ float ps[8 * 64];

  qs[wid * 64 + lane] = qkv[(size_t)(b * T_ + q) * E3_ + h * 64 + lane];

  float m = -INFINITY, l = 0.0f, acc = 0.0f;
  const int ntiles = (qbase + 7) / 64 + 1;

  for (int kt = 0; kt < ntiles; ++kt) {
    __syncthreads();
    // stage K and V tiles (64 keys x 64 dims each)
    for (int i = threadIdx.x; i < 64 * 16; i += 512) {
      const int kk = i >> 4;
      const int c  = i & 15;
      const float* kp = qkv + (size_t)(b * T_ + kt * 64 + kk) * E3_ + h * 64;
      float4 kv = *(const float4*)(kp + E_  + c * 4);
      float4 vv = *(const float4*)(kp + 2*E_ + c * 4);
      ((float4*)Ks)[kk * 16 + (c ^ (kk & 15))] = kv;   // swizzled
      ((float4*)Vs)[kk * 16 + c] = vv;
    }
    __syncthreads();

    if (kt * 64 <= q) {
      // scores: lane = key index within tile
      float s = 0.0f;
      const float4* q4 = (const float4*)(qs + wid * 64);
      const float4* k4 = ((const float4*)Ks) + lane * 16;
      #pragma unroll
      for (int j = 0; j < 16; ++j) {
        float4 qv = q4[j];
        float4 kv = k4[j ^ (lane & 15)];
        s = fmaf(qv.x, kv.x, s); s = fmaf(qv.y, kv.y, s);
        s = fmaf(qv.z, kv.z, s); s = fmaf(qv.w, kv.w, s);
      }
      s *= 0.125f;                       // 1/sqrt(64)
      const int kg = kt * 64 + lane;
      if (kg > q) s = -INFINITY;
      // wave allreduce max
      float mx = s;
      #pragma unroll
      for (int off = 32; off; off >>= 1) mx = fmaxf(mx, __shfl_xor(mx, off));
      const float mn = fmaxf(m, mx);
      const float p = __expf(s - mn);    // masked -> 0
      float psum = p;
      #pragma unroll
      for (int off = 32; off; off >>= 1) psum += __shfl_xor(psum, off);
      const float alpha = __expf(m - mn);
      l = l * alpha + psum;
      acc *= alpha;
      m = mn;
      ps[wid * 64 + lane] = p;
      // PV: lane = output dim d
      const float4* p4 = (const float4*)(ps + wid * 64);
      #pragma unroll
      for (int jj = 0; jj < 16; ++jj) {
        float4 pv = p4[jj];
        acc = fmaf(pv.x, Vs[(jj*4 + 0) * 64 + lane], acc);
        acc = fmaf(pv.y, Vs[(jj*4 + 1) * 64 + lane], acc);
        acc = fmaf(pv.z, Vs[(jj*4 + 2) * 64 + lane], acc);
        acc = fmaf(pv.w, Vs[(jj*4 + 3) * 64 + lane], acc);
      }
    }
  }
  y[(size_t)(b * T_ + q) * E_ + h * 64 + lane] = acc / l;
}

// ---------------- driver ----------------
extern "C" void kernel_launch(void* const* d_in, const int* in_sizes, int n_in,
                              void* d_out, int out_size, void* d_ws, size_t ws_size,
                              hipStream_t stream)
{
  (void)in_sizes; (void)n_in; (void)out_size; (void)ws_size;
  const int*   idx    = (const int*)  d_in[0];
  const float* wte    = (const float*)d_in[1];
  const float* wpe    = (const float*)d_in[2];
  const float* ln1_g  = (const float*)d_in[3];
  const float* ln1_b  = (const float*)d_in[4];
  const float* attn_w = (const float*)d_in[5];
  const float* attn_b = (const float*)d_in[6];
  const float* proj_w = (const float*)d_in[7];
  const float* proj_b = (const float*)d_in[8];
  const float* ln2_g  = (const float*)d_in[9];
  const float* ln2_b  = (const float*)d_in[10];
  const float* fc_w   = (const float*)d_in[11];
  const float* fc_b   = (const float*)d_in[12];
  const float* fc2_w  = (const float*)d_in[13];
  const float* fc2_b  = (const float*)d_in[14];
  const float* lnf_g  = (const float*)d_in[15];
  const float* lnf_b  = (const float*)d_in[16];
  float* out = (float*)d_out;

  char* ws = (char*)d_ws;
  float* x   = (float*)(ws + 0);          //  4 MB: [2048, 512]
  float* h   = (float*)(ws + 4194304);    //  4 MB: [2048, 512]
  float* qkv = (float*)(ws + 8388608);    // 12 MB: [2048, 1536]
  float* y   = (float*)(ws + 20971520);   //  4 MB: [2048, 512]
  float* u   = (float*)(ws + 25165824);   // 16 MB: [2048, 2048]

  embed_kernel<<<dim3(M_ROWS), dim3(128), 0, stream>>>(idx, wte, wpe, x);

  for (int l = 0; l < L_; ++l) {
    ln_kernel<<<dim3(M_ROWS), dim3(64), 0, stream>>>(
        x, ln1_g + l * E_, ln1_b + l * E_, h);
    gemm_kernel<64,64,4,4,false,false,false>
        <<<dim3(E3_/64, M_ROWS/64), 256, 0, stream>>>(
        h, attn_w + (size_t)l * E_ * E3_, attn_b + (size_t)l * E3_,
        nullptr, qkv, M_ROWS, E3_, E_);
    attn_kernel<<<dim3(T_/8, B_*H_), 512, 0, stream>>>(qkv, y);
    gemm_kernel<64,64,4,4,false,false,true>
        <<<dim3(E_/64, M_ROWS/64), 256, 0, stream>>>(
        y, proj_w + (size_t)l * E_ * E_, proj_b + (size_t)l * E_,
        x, x, M_ROWS, E_, E_);
    ln_kernel<<<dim3(M_ROWS), dim3(64), 0, stream>>>(
        x, ln2_g + l * E_, ln2_b + l * E_, h);
    gemm_kernel<64,64,4,4,false,true,false>
        <<<dim3(E4_/64, M_ROWS/64), 256, 0, stream>>>(
        h, fc_w + (size_t)l * E_ * E4_, fc_b + (size_t)l * E4_,
        nullptr, u, M_ROWS, E4_, E_);
    gemm_kernel<64,64,4,4,false,false,true>
        <<<dim3(E_/64, M_ROWS/64), 256, 0, stream>>>(
        u, fc2_w + (size_t)l * E4_ * E_, fc2_b + (size_t)l * E_,
        x, x, M_ROWS, E_, E4_);
  }

  ln_kernel<<<dim3(M_ROWS), dim3(64), 0, stream>>>(x, lnf_g, lnf_b, h);
  gemm_kernel<128,128,8,8,true,false,false>
      <<<dim3((V_ + 127)/128, M_ROWS/128), 256, 0, stream>>>(
      h, wte, nullptr, nullptr, out, M_ROWS, V_, E_);
}

// Round 2
// 2216.714 us; speedup vs baseline: 2.1455x; 2.1455x over previous
//
#include <hip/hip_runtime.h>
#include <hip/hip_bf16.h>
#include <math.h>

#define V_ 50257
#define L_ 6
#define H_ 8
#define E_ 512
#define B_ 2
#define T_ 1024
#define M_ROWS (B_*T_)   /* 2048 */
#define E3_ (3*E_)       /* 1536 */
#define E4_ (4*E_)       /* 2048 */

typedef short bf16x8 __attribute__((ext_vector_type(8)));
typedef float f32x4 __attribute__((ext_vector_type(4)));

// ---------------- embedding: x = wte[idx] + wpe[t] (fp32) ----------------
__global__ __launch_bounds__(128) void embed_kernel(
    const int* __restrict__ idx, const float* __restrict__ wte,
    const float* __restrict__ wpe, float* __restrict__ x)
{
  const int row = blockIdx.x;
  const int t = row & (T_ - 1);
  const int tok = idx[row];
  float4 a = ((const float4*)(wte + (size_t)tok * E_))[threadIdx.x];
  float4 p = ((const float4*)(wpe + (size_t)t * E_))[threadIdx.x];
  float4 o; o.x = a.x + p.x; o.y = a.y + p.y; o.z = a.z + p.z; o.w = a.w + p.w;
  ((float4*)(x + (size_t)row * E_))[threadIdx.x] = o;
}

// ---------------- layernorm fp32 -> bf16, one wave per row ----------------
__global__ __launch_bounds__(64) void ln_kernel(
    const float* __restrict__ x, const float* __restrict__ g,
    const float* __restrict__ b, __hip_bfloat16* __restrict__ out)
{
  const int row = blockIdx.x;
  const int lane = threadIdx.x;
  const float4* xr = (const float4*)(x + (size_t)row * E_);
  float4 v0 = xr[lane * 2];
  float4 v1 = xr[lane * 2 + 1];
  float s = v0.x + v0.y + v0.z + v0.w + v1.x + v1.y + v1.z + v1.w;
  float q = v0.x*v0.x + v0.y*v0.y + v0.z*v0.z + v0.w*v0.w
          + v1.x*v1.x + v1.y*v1.y + v1.z*v1.z + v1.w*v1.w;
  #pragma unroll
  for (int off = 32; off; off >>= 1) {
    s += __shfl_xor(s, off);
    q += __shfl_xor(q, off);
  }
  const float mean = s * (1.0f / E_);
  const float var  = q * (1.0f / E_) - mean * mean;
  const float rs   = 1.0f / sqrtf(var + 1e-5f);
  const float4* g4 = (const float4*)g;
  const float4* b4 = (const float4*)b;
  float4 G0 = g4[lane*2], G1 = g4[lane*2+1];
  float4 B0 = b4[lane*2], B1 = b4[lane*2+1];
  union { __hip_bfloat16 h[8]; uint4 q4; } pk;
  pk.h[0] = __float2bfloat16((v0.x - mean) * rs * G0.x + B0.x);
  pk.h[1] = __float2bfloat16((v0.y - mean) * rs * G0.y + B0.y);
  pk.h[2] = __float2bfloat16((v0.z - mean) * rs * G0.z + B0.z);
  pk.h[3] = __float2bfloat16((v0.w - mean) * rs * G0.w + B0.w);
  pk.h[4] = __float2bfloat16((v1.x - mean) * rs * G1.x + B1.x);
  pk.h[5] = __float2bfloat16((v1.y - mean) * rs * G1.y + B1.y);
  pk.h[6] = __float2bfloat16((v1.z - mean) * rs * G1.z + B1.z);
  pk.h[7] = __float2bfloat16((v1.w - mean) * rs * G1.w + B1.w);
  ((uint4*)(out + (size_t)row * E_))[lane] = pk.q4;
}

// ---------------- transpose + fp32->bf16 convert: W[l][K][N] -> Wt[l][N][K] ----------------
__global__ __launch_bounds__(256) void transpose_cvt(
    const float* __restrict__ W, __hip_bfloat16* __restrict__ Wt, int K, int N)
{
  __shared__ float t[32][33];
  const size_t lsz = (size_t)K * N;
  const float* Wl = W + (size_t)blockIdx.z * lsz;
  __hip_bfloat16* Wtl = Wt + (size_t)blockIdx.z * lsz;
  const int k0 = blockIdx.y * 32, n0 = blockIdx.x * 32;
  for (int r = threadIdx.y; r < 32; r += 8)
    t[r][threadIdx.x] = Wl[(size_t)(k0 + r) * N + n0 + threadIdx.x];
  __syncthreads();
  for (int r = threadIdx.y; r < 32; r += 8)
    Wtl[(size_t)(n0 + r) * K + k0 + threadIdx.x] = __float2bfloat16(t[threadIdx.x][r]);
}

// ---------------- exact GELU ----------------
__device__ __forceinline__ float gelu_exact(float v) {
  return 0.5f * v * (1.0f + erff(v * 0.70710678118654752f));
}

// ---------------- MFMA bf16 GEMM (m97 structure) ----------------
// C[M,N] = act(A[M,K]_bf16 @ B + bias) (+res). B source: Bt[N,K] bf16
// (BF32=false) or Bf[N,K] fp32 reg-stage-converted (BF32=true, lm_head).
// BK=64, 4 waves (WR x WC), 16x16x32 MFMA. M%BM==0, K%64==0; N guarded
// only on the BF32 path (bf16 path requires N%BN==0).
template<int BM, int BN, int WR, int WC, bool BF32, bool GELU, bool RES, bool OBF16, bool SWZ>
__global__ __launch_bounds__(256) void mm_kernel(
    const __hip_bfloat16* __restrict__ A, const void* __restrict__ Bsrc,
    const float* __restrict__ bias, const float* __restrict__ res,
    void* __restrict__ Cout, int M, int N, int K)
{
  constexpr int MR = BM / (WR * 16);
  constexpr int NR = BN / (WC * 16);
  __shared__ __align__(16) __hip_bfloat16 As[BM * 64];
  __shared__ __align__(16) __hip_bfloat16 Bs[BN * 64];
  const int tid = threadIdx.x;
  const int lane = tid & 63;
  const int wid = tid >> 6;
  const int wr = wid / WC;
  const int wc = wid % WC;
  int bx = blockIdx.x, by = blockIdx.y;
  if constexpr (SWZ) {   // bijective XCD swizzle (nwg % 8 == 0)
    const int nwg = gridDim.x * gridDim.y;
    const int wg = by * gridDim.x + bx;
    const int cpx = nwg >> 3;
    const int sw = (wg & 7) * cpx + (wg >> 3);
    bx = sw % gridDim.x;
    by = sw / gridDim.x;
  }
  const int m0 = by * BM;
  const int n0 = bx * BN;
  const int l15 = lane & 15;
  const int l4 = lane >> 4;

  f32x4 acc[MR][NR] = {};

  for (int kt = 0; kt < K; kt += 64) {
    // ---- stage A tile [BM][64] via global_load_lds (16B/lane) ----
    #pragma unroll
    for (int c = 0; c < BM * 8 / 256; ++c) {
      const int s = c * 256 + tid;
      const __hip_bfloat16* g = A + (size_t)(m0 + (s >> 3)) * K + kt + (s & 7) * 8;
      __builtin_amdgcn_global_load_lds(
          (const __attribute__((address_space(1))) unsigned int*)g,
          (__attribute__((address_space(3))) unsigned int*)(As + s * 8), 16, 0, 0);
    }
    // ---- stage B tile [BN][64] ----
    if constexpr (!BF32) {
      const __hip_bfloat16* Bt = (const __hip_bfloat16*)Bsrc;
      #pragma unroll
      for (int c = 0; c < BN * 8 / 256; ++c) {
        const int s = c * 256 + tid;
        const __hip_bfloat16* g = Bt + (size_t)(n0 + (s >> 3)) * K + kt + (s & 7) * 8;
        __builtin_amdgcn_global_load_lds(
            (const __attribute__((address_space(1))) unsigned int*)g,
            (__attribute__((address_space(3))) unsigned int*)(Bs + s * 8), 16, 0, 0);
      }
    } else {
      const float* Bf = (const float*)Bsrc;
      #pragma unroll
      for (int c = 0; c < BN * 8 / 256; ++c) {
        const int s = c * 256 + tid;
        int row = n0 + (s >> 3);
        if (row > N - 1) row = N - 1;
        const float* g = Bf + (size_t)row * K + kt + (s & 7) * 8;
        float4 u0 = *(const float4*)g;
        float4 u1 = *(const float4*)(g + 4);
        union { __hip_bfloat16 b[8]; uint4 q; } pk;
        pk.b[0] = __float2bfloat16(u0.x); pk.b[1] = __float2bfloat16(u0.y);
        pk.b[2] = __float2bfloat16(u0.z); pk.b[3] = __float2bfloat16(u0.w);
        pk.b[4] = __float2bfloat16(u1.x); pk.b[5] = __float2bfloat16(u1.y);
        pk.b[6] = __float2bfloat16(u1.z); pk.b[7] = __float2bfloat16(u1.w);
        *(uint4*)(Bs + s * 8) = pk.q;
      }
    }
    __syncthreads();
    // ---- fragments + MFMA ----
    #pragma unroll
    for (int kk = 0; kk < 2; ++kk) {
      bf16x8 af[MR], bf[NR];
      #pragma unroll
      for (int i = 0; i < MR; ++i)
        af[i] = *(const bf16x8*)(As + (wr * MR * 16 + i * 16 + l15) * 64 + kk * 32 + l4 * 8);
      #pragma unroll
      for (int j = 0; j < NR; ++j)
        bf[j] = *(const bf16x8*)(Bs + (wc * NR * 16 + j * 16 + l15) * 64 + kk * 32 + l4 * 8);
      #pragma unroll
      for (int i = 0; i < MR; ++i)
        #pragma unroll
        for (int j = 0; j < NR; ++j)
          acc[i][j] = __builtin_amdgcn_mfma_f32_16x16x32_bf16(af[i], bf[j], acc[i][j], 0, 0, 0);
    }
    __syncthreads();
  }
  // ---- epilogue: row = (lane>>4)*4 + r, col = lane&15 (m89-verified) ----
  #pragma unroll
  for (int i = 0; i < MR; ++i) {
    const int rbase = m0 + wr * MR * 16 + i * 16 + l4 * 4;
    #pragma unroll
    for (int j = 0; j < NR; ++j) {
      const int col = n0 + wc * NR * 16 + j * 16 + l15;
      if (col < N) {
        const float bv = bias ? bias[col] : 0.0f;
        #pragma unroll
        for (int r = 0; r < 4; ++r) {
          float v = acc[i][j][r] + bv;
          if constexpr (GELU) v = gelu_exact(v);
          if constexpr (RES)  v += res[(size_t)(rbase + r) * N + col];
          if constexpr (OBF16)
            ((__hip_bfloat16*)Cout)[(size_t)(rbase + r) * N + col] = __float2bfloat16(v);
          else
            ((float*)Cout)[(size_t)(rbase + r) * N + col] = v;
        }
      }
    }
  }
}

// ---------------- fused causal flash attention (fp32 math, bf16 out) ----------------
__global__ __launch_bounds__(512) void attn_kernel(
    const float* __restrict__ qkv, __hip_bfloat16* __restrict__ y)
{
  const int bh = blockIdx.y;
  const int b  = bh >> 3;
  const int h  = bh & 7;
  const int qbase = blockIdx.x * 8;
  const int wid  = threadIdx.x >> 6;
  const int lane = threadIdx.x & 63;
  const int q = qbase + wid;

  __shared__ float Ks[64 * 64];
  __shared__ float Vs[64 * 64];
  __shared__ float qs[8 * 64];
  __shared__ float ps[8 * 64];

  qs[wid * 64 + lane] = qkv[(size_t)(b * T_ + q) * E3_ + h * 64 + lane];

  float m = -INFINITY, l = 0.0f, acc = 0.0f;
  const int ntiles = (qbase + 7) / 64 + 1;

  for (int kt = 0; kt < ntiles; ++kt) {
    __syncthreads();
    for (int i = threadIdx.x; i < 64 * 16; i += 512) {
      const int kk = i >> 4;
      const int c  = i & 15;
      const float* kp = qkv + (size_t)(b * T_ + kt * 64 + kk) * E3_ + h * 64;
      float4 kv = *(const float4*)(kp + E_  + c * 4);
      float4 vv = *(const float4*)(kp + 2*E_ + c * 4);
      ((float4*)Ks)[kk * 16 + (c ^ (kk & 15))] = kv;
      ((float4*)Vs)[kk * 16 + c] = vv;
    }
    __syncthreads();

    if (kt * 64 <= q) {
      float s = 0.0f;
      const float4* q4 = (const float4*)(qs + wid * 64);
      const float4* k4 = ((const float4*)Ks) + lane * 16;
      #pragma unroll
      for (int j = 0; j < 16; ++j) {
        float4 qv = q4[j];
        float4 kv = k4[j ^ (lane & 15)];
        s = fmaf(qv.x, kv.x, s); s = fmaf(qv.y, kv.y, s);
        s = fmaf(qv.z, kv.z, s); s = fmaf(qv.w, kv.w, s);
      }
      s *= 0.125f;
      const int kg = kt * 64 + lane;
      if (kg > q) s = -INFINITY;
      float mx = s;
      #pragma unroll
      for (int off = 32; off; off >>= 1) mx = fmaxf(mx, __shfl_xor(mx, off));
      const float mn = fmaxf(m, mx);
      const float p = __expf(s - mn);
      float psum = p;
      #pragma unroll
      for (int off = 32; off; off >>= 1) psum += __shfl_xor(psum, off);
      const float alpha = __expf(m - mn);
      l = l * alpha + psum;
      acc *= alpha;
      m = mn;
      ps[wid * 64 + lane] = p;
      const float4* p4 = (const float4*)(ps + wid * 64);
      #pragma unroll
      for (int jj = 0; jj < 16; ++jj) {
        float4 pv = p4[jj];
        acc = fmaf(pv.x, Vs[(jj*4 + 0) * 64 + lane], acc);
        acc = fmaf(pv.y, Vs[(jj*4 + 1) * 64 + lane], acc);
        acc = fmaf(pv.z, Vs[(jj*4 + 2) * 64 + lane], acc);
        acc = fmaf(pv.w, Vs[(jj*4 + 3) * 64 + lane], acc);
      }
    }
  }
  y[(size_t)(b * T_ + q) * E_ + h * 64 + lane] = __float2bfloat16(acc / l);
}

// ---------------- driver ----------------
extern "C" void kernel_launch(void* const* d_in, const int* in_sizes, int n_in,
                              void* d_out, int out_size, void* d_ws, size_t ws_size,
                              hipStream_t stream)
{
  (void)in_sizes; (void)n_in; (void)out_size; (void)ws_size;
  const int*   idx    = (const int*)  d_in[0];
  const float* wte    = (const float*)d_in[1];
  const float* wpe    = (const float*)d_in[2];
  const float* ln1_g  = (const float*)d_in[3];
  const float* ln1_b  = (const float*)d_in[4];
  const float* attn_w = (const float*)d_in[5];
  const float* attn_b = (const float*)d_in[6];
  const float* proj_w = (const float*)d_in[7];
  const float* proj_b = (const float*)d_in[8];
  const float* ln2_g  = (const float*)d_in[9];
  const float* ln2_b  = (const float*)d_in[10];
  const float* fc_w   = (const float*)d_in[11];
  const float* fc_b   = (const float*)d_in[12];
  const float* fc2_w  = (const float*)d_in[13];
  const float* fc2_b  = (const float*)d_in[14];
  const float* lnf_g  = (const float*)d_in[15];
  const float* lnf_b  = (const float*)d_in[16];
  float* out = (float*)d_out;

  char* ws = (char*)d_ws;
  float*          x     = (float*)(ws + 0);                 //  4 MB [2048,512] f32
  __hip_bfloat16* h     = (__hip_bfloat16*)(ws + 4194304);  //  2 MB [2048,512] bf16
  float*          qkv   = (float*)(ws + 6291456);           // 12 MB [2048,1536] f32
  __hip_bfloat16* y     = (__hip_bfloat16*)(ws + 18874368); //  2 MB [2048,512] bf16
  __hip_bfloat16* u     = (__hip_bfloat16*)(ws + 20971520); //  8 MB [2048,2048] bf16
  __hip_bfloat16* aw_t  = (__hip_bfloat16*)(ws + 29360128); //  9.4 MB [6][1536][512]
  __hip_bfloat16* pw_t  = (__hip_bfloat16*)(ws + 38797312); //  3.1 MB [6][512][512]
  __hip_bfloat16* fw_t  = (__hip_bfloat16*)(ws + 41943040); // 12.6 MB [6][2048][512]
  __hip_bfloat16* f2w_t = (__hip_bfloat16*)(ws + 54525952); // 12.6 MB [6][512][2048]

  // weight convert+transpose (every call; ws is re-poisoned each launch)
  transpose_cvt<<<dim3(E3_/32, E_/32, L_), dim3(32,8), 0, stream>>>(attn_w, aw_t, E_, E3_);
  transpose_cvt<<<dim3(E_/32,  E_/32, L_), dim3(32,8), 0, stream>>>(proj_w, pw_t, E_, E_);
  transpose_cvt<<<dim3(E4_/32, E_/32, L_), dim3(32,8), 0, stream>>>(fc_w,   fw_t, E_, E4_);
  transpose_cvt<<<dim3(E_/32, E4_/32, L_), dim3(32,8), 0, stream>>>(fc2_w, f2w_t, E4_, E_);

  embed_kernel<<<dim3(M_ROWS), dim3(128), 0, stream>>>(idx, wte, wpe, x);

  for (int l = 0; l < L_; ++l) {
    ln_kernel<<<dim3(M_ROWS), dim3(64), 0, stream>>>(
        x, ln1_g + l * E_, ln1_b + l * E_, h);
    mm_kernel<128,128,2,2,false,false,false,false,false>
        <<<dim3(E3_/128, M_ROWS/128), 256, 0, stream>>>(
        h, aw_t + (size_t)l * E_ * E3_, attn_b + (size_t)l * E3_,
        nullptr, qkv, M_ROWS, E3_, E_);
    attn_kernel<<<dim3(T_/8, B_*H_), 512, 0, stream>>>(qkv, y);
    mm_kernel<64,64,2,2,false,false,true,false,false>
        <<<dim3(E_/64, M_ROWS/64), 256, 0, stream>>>(
        y, pw_t + (size_t)l * E_ * E_, proj_b + (size_t)l * E_,
        x, x, M_ROWS, E_, E_);
    ln_kernel<<<dim3(M_ROWS), dim3(64), 0, stream>>>(
        x, ln2_g + l * E_, ln2_b + l * E_, h);
    mm_kernel<128,128,2,2,false,true,false,true,false>
        <<<dim3(E4_/128, M_ROWS/128), 256, 0, stream>>>(
        h, fw_t + (size_t)l * E_ * E4_, fc_b + (size_t)l * E4_,
        nullptr, u, M_ROWS, E4_, E_);
    mm_kernel<64,64,2,2,false,false,true,false,false>
        <<<dim3(E_/64, M_ROWS/64), 256, 0, stream>>>(
        u, f2w_t + (size_t)l * E4_ * E_, fc2_b + (size_t)l * E_,
        x, x, M_ROWS, E_, E4_);
  }

  ln_kernel<<<dim3(M_ROWS), dim3(64), 0, stream>>>(x, lnf_g, lnf_b, h);
  mm_kernel<128,128,2,2,true,false,false,false,true>
      <<<dim3((V_ + 127)/128, M_ROWS/128), 256, 0, stream>>>(
      h, wte, nullptr, nullptr, out, M_ROWS, V_, E_);
}